// Round 1
// baseline (285.504 us; speedup 1.0000x reference)
//
#include <hip/hip_runtime.h>

// SCAM fused kernel for MI355X (gfx950).
// One workgroup per (b,h) attention slice; everything (LN, 4 projections,
// QK^T, dual softmax, 2x PV, epilogue) stays in LDS.

typedef __attribute__((ext_vector_type(8))) short bhalf8;   // 8 bf16 in 4 VGPRs
typedef __attribute__((ext_vector_type(4))) float f32x4;

#define DEVI static __device__ __forceinline__

constexpr int Cc   = 192;
constexpr int HWc  = 9216;          // 96*96
constexpr int CHW  = 192 * 9216;    // per-batch image
constexpr int HALF_OUT = 16 * CHW;  // 28311552

DEVI unsigned short f2bf(float f) {           // round-to-nearest-even fp32->bf16
  unsigned u = __builtin_bit_cast(unsigned, f);
  u += 0x7fffu + ((u >> 16) & 1u);
  return (unsigned short)(u >> 16);
}
DEVI float bf2f(unsigned short h) {
  unsigned u = (unsigned)h << 16;
  return __builtin_bit_cast(float, u);
}
DEVI float bf2f_s(short h) { return bf2f((unsigned short)h); }

// ---------------------------------------------------------------- setup 1 ---
// blocks [0,576): bf16 weight prep (W1l'=lnw_l*Wl1, W1r'=lnw_r*Wr1, Wl2, Wr2)
// blocks 576/577: LN-fold row sums s1/t1
// blocks [578,610): mish(t)
__global__ void setup1(
    const float* __restrict__ t,
    const float* __restrict__ lnwl, const float* __restrict__ lnbl,
    const float* __restrict__ lnwr, const float* __restrict__ lnbr,
    const float* __restrict__ Wl1, const float* __restrict__ bl1,
    const float* __restrict__ Wr1, const float* __restrict__ br1,
    const float* __restrict__ Wl2, const float* __restrict__ Wr2,
    short* __restrict__ W1l_b, short* __restrict__ W1r_b,
    short* __restrict__ W2l_b, short* __restrict__ W2r_b,
    float* __restrict__ s1l, float* __restrict__ t1l,
    float* __restrict__ s1r, float* __restrict__ t1r,
    float* __restrict__ mt)
{
  const int blk = blockIdx.x, tid = threadIdx.x;
  if (blk < 576) {
    int id  = blk * 256 + tid;          // < 147456
    int m   = id / 36864;
    int rem = id - m * 36864;
    int c   = rem % 192;
    float v;
    short* dst;
    if (m == 0)      { v = lnwl[c] * Wl1[rem]; dst = W1l_b; }
    else if (m == 1) { v = lnwr[c] * Wr1[rem]; dst = W1r_b; }
    else if (m == 2) { v = Wl2[rem];           dst = W2l_b; }
    else             { v = Wr2[rem];           dst = W2r_b; }
    dst[rem] = (short)f2bf(v);
  } else if (blk == 576 || blk == 577) {
    if (tid < 192) {
      const float* Wm = (blk == 576) ? Wl1 : Wr1;
      const float* lw = (blk == 576) ? lnwl : lnwr;
      const float* lb = (blk == 576) ? lnbl : lnbr;
      const float* bb = (blk == 576) ? bl1 : br1;
      float s = 0.f, tb = 0.f;
      for (int c = 0; c < 192; ++c) {
        float wv = Wm[tid * 192 + c];
        s  += lw[c] * wv;
        tb += lb[c] * wv;
      }
      if (blk == 576) { s1l[tid] = s; t1l[tid] = tb + bb[tid]; }
      else            { s1r[tid] = s; t1r[tid] = tb + bb[tid]; }
    }
  } else {
    int id = (blk - 578) * 256 + tid;   // < 8192
    float v = t[id];
    float sp = (v > 20.f) ? v : log1pf(__expf(v));
    mt[id] = v * tanhf(sp);
  }
}

// temb[b][o] = sum_k mish(t)[b][k] * Wt[o][k] + bt[o]
__global__ void setup2(const float* __restrict__ mt, const float* __restrict__ Wt,
                       const float* __restrict__ bt, float* __restrict__ temb)
{
  int id = blockIdx.x * 256 + threadIdx.x;  // < 3072
  int b = id / 192, o = id - b * 192;
  float s = 0.f;
  for (int k = 0; k < 512; ++k) s += mt[b * 512 + k] * Wt[o * 512 + k];
  temb[id] = s + bt[o];
}

// ------------------------------------------------------------- main kernel ---
// misc layout (floats): 0 mu_l[96], 96 rs_l[96], 192 mu_r[96], 288 rs_r[96],
// 384 s1l, 576 t1l, 768 s1r, 960 t1r, 1152 bvl, 1344 bvr,
// 1536 te, 1728 beta, 1920 gamma   (end 2112)
struct SmemT {
  short buf1[96 * 200];   // XT_l -> Q_l -> att(fp32 alias) -> F_r2l
  short buf2[96 * 200];   // XT_r -> Q_r -> P_row/P_colT -> F_l2r
  short vtl[192 * 96];    // V_l^T [c][x]
  short vtr[192 * 96];    // V_r^T [c][y]
  float misc[2112];
};
static_assert(sizeof(SmemT) <= 163840, "LDS overflow");

__launch_bounds__(768, 3)
__global__ void scam_main(
    const float* __restrict__ x_l, const float* __restrict__ x_r,
    const float* __restrict__ bl2, const float* __restrict__ br2,
    const float* __restrict__ beta, const float* __restrict__ gamma,
    const short* __restrict__ W1l_b, const short* __restrict__ W1r_b,
    const short* __restrict__ W2l_b, const short* __restrict__ W2r_b,
    const float* __restrict__ s1l, const float* __restrict__ t1l,
    const float* __restrict__ s1r, const float* __restrict__ t1r,
    const float* __restrict__ temb,
    float* __restrict__ out)
{
  __shared__ SmemT sm;
  const int tid  = threadIdx.x;
  const int lane = tid & 63;
  const int wid  = tid >> 6;            // 0..11
  const int m16  = lane & 15;
  const int kc8  = (lane >> 4) * 8;     // element offset within a fragment row
  const int r4   = (lane >> 4) * 4;     // D-row base
  const int slice = blockIdx.x;
  const int bb_ = slice / 96;
  const int hh_ = slice - bb_ * 96;
  const int sliceBase = bb_ * CHW + hh_ * 96;

  // phase 0: misc vectors into LDS
  for (int idx = tid; idx < 1728; idx += 768) {
    int a = idx / 192, o = idx - a * 192;
    switch (a) {
      case 0: sm.misc[1536 + o] = temb[bb_ * 192 + o]; break;
      case 1: sm.misc[384 + o]  = s1l[o]; break;
      case 2: sm.misc[576 + o]  = t1l[o]; break;
      case 3: sm.misc[768 + o]  = s1r[o]; break;
      case 4: sm.misc[960 + o]  = t1r[o]; break;
      case 5: sm.misc[1152 + o] = bl2[o]; break;
      case 6: sm.misc[1344 + o] = br2[o]; break;
      case 7: sm.misc[1728 + o] = beta[o]; break;
      default: sm.misc[1920 + o] = gamma[o]; break;
    }
  }

  // phase 1: stage x -> bf16 pixel-major [w][c] (stride 200 halves)
  #pragma unroll
  for (int j = 0; j < 6; ++j) {
    int i4 = j * 768 + tid;             // < 4608
    int c  = i4 / 24;
    int w4 = i4 - c * 24;
    const float4 xl4 = *reinterpret_cast<const float4*>(x_l + sliceBase + c * HWc + w4 * 4);
    const float4 xr4 = *reinterpret_cast<const float4*>(x_r + sliceBase + c * HWc + w4 * 4);
    int base = w4 * 4 * 200 + c;
    sm.buf1[base      ] = (short)f2bf(xl4.x);
    sm.buf1[base + 200] = (short)f2bf(xl4.y);
    sm.buf1[base + 400] = (short)f2bf(xl4.z);
    sm.buf1[base + 600] = (short)f2bf(xl4.w);
    sm.buf2[base      ] = (short)f2bf(xr4.x);
    sm.buf2[base + 200] = (short)f2bf(xr4.y);
    sm.buf2[base + 400] = (short)f2bf(xr4.z);
    sm.buf2[base + 600] = (short)f2bf(xr4.w);
  }
  __syncthreads();

  // phase 2: LN stats per pixel (from bf16 LDS copy)
  {
    int side = (tid >= 384) ? 1 : 0;
    int rest = tid - side * 384;
    int w = rest >> 2;
    int q = rest & 3;
    const short* Xb = side ? sm.buf2 : sm.buf1;
    float s0 = 0.f, s2 = 0.f;
    #pragma unroll
    for (int mc = 0; mc < 6; ++mc) {
      bhalf8 v = *reinterpret_cast<const bhalf8*>(Xb + w * 200 + q * 48 + mc * 8);
      #pragma unroll
      for (int e = 0; e < 8; ++e) { float f = bf2f_s(v[e]); s0 += f; s2 += f * f; }
    }
    s0 += __shfl_xor(s0, 1); s2 += __shfl_xor(s2, 1);
    s0 += __shfl_xor(s0, 2); s2 += __shfl_xor(s2, 2);
    if (q == 0) {
      float mu  = s0 * (1.f / 192.f);
      float var = s2 * (1.f / 192.f) - mu * mu;
      float rs  = rsqrtf(var + 1e-6f);
      sm.misc[side * 192 + w]      = mu;
      sm.misc[side * 192 + 96 + w] = rs;
    }
  }
  __syncthreads();

  // phase 3: V^T = W2 * X^T  -> vtl/vtr   (D[m=c][n=x])
  #pragma unroll
  for (int sd = 0; sd < 2; ++sd) {
    const short* Wb = sd ? W2r_b : W2l_b;
    const short* Xb = sd ? sm.buf2 : sm.buf1;
    short* Vt = sd ? sm.vtr : sm.vtl;
    const float* bv = sm.misc + 1152 + sd * 192;
    const int crow = wid * 16 + m16;
    bhalf8 af[6];
    #pragma unroll
    for (int k = 0; k < 6; ++k)
      af[k] = *reinterpret_cast<const bhalf8*>(Wb + crow * 192 + k * 32 + kc8);
    #pragma unroll
    for (int xi = 0; xi < 6; ++xi) {
      f32x4 acc = {0.f, 0.f, 0.f, 0.f};
      #pragma unroll
      for (int k = 0; k < 6; ++k) {
        bhalf8 bfr = *reinterpret_cast<const bhalf8*>(Xb + (xi * 16 + m16) * 200 + k * 32 + kc8);
        acc = __builtin_amdgcn_mfma_f32_16x16x32_bf16(af[k], bfr, acc, 0, 0, 0);
      }
      const int xcol = xi * 16 + m16;
      #pragma unroll
      for (int j = 0; j < 4; ++j) {
        int cr = wid * 16 + r4 + j;
        Vt[cr * 96 + xcol] = (short)f2bf(acc[j] + bv[cr]);
      }
    }
  }

  // phase 4: Q projections into registers (D[m=x][n=o])
  f32x4 accQ0[6], accQ1[6];
  {
    const int orow = wid * 16 + m16;
    {
      bhalf8 bfq[6];
      #pragma unroll
      for (int k = 0; k < 6; ++k)
        bfq[k] = *reinterpret_cast<const bhalf8*>(W1l_b + orow * 192 + k * 32 + kc8);
      #pragma unroll
      for (int mi = 0; mi < 6; ++mi) {
        f32x4 acc = {0.f, 0.f, 0.f, 0.f};
        #pragma unroll
        for (int k = 0; k < 6; ++k) {
          bhalf8 afr = *reinterpret_cast<const bhalf8*>(sm.buf1 + (mi * 16 + m16) * 200 + k * 32 + kc8);
          acc = __builtin_amdgcn_mfma_f32_16x16x32_bf16(afr, bfq[k], acc, 0, 0, 0);
        }
        accQ0[mi] = acc;
      }
    }
    {
      bhalf8 bfq[6];
      #pragma unroll
      for (int k = 0; k < 6; ++k)
        bfq[k] = *reinterpret_cast<const bhalf8*>(W1r_b + orow * 192 + k * 32 + kc8);
      #pragma unroll
      for (int mi = 0; mi < 6; ++mi) {
        f32x4 acc = {0.f, 0.f, 0.f, 0.f};
        #pragma unroll
        for (int k = 0; k < 6; ++k) {
          bhalf8 afr = *reinterpret_cast<const bhalf8*>(sm.buf2 + (mi * 16 + m16) * 200 + k * 32 + kc8);
          acc = __builtin_amdgcn_mfma_f32_16x16x32_bf16(afr, bfq[k], acc, 0, 0, 0);
        }
        accQ1[mi] = acc;
      }
    }
  }
  __syncthreads();
  // write Q with folded LayerNorm affine: Q = rs*acc - mu*rs*s1[o] + t1[o]
  {
    const int o = wid * 16 + m16;
    #pragma unroll
    for (int sd = 0; sd < 2; ++sd) {
      short* Qb = sd ? sm.buf2 : sm.buf1;
      const float* muA = sm.misc + sd * 192;
      const float* rsA = muA + 96;
      float s1o = sm.misc[384 + sd * 384 + o];
      float t1o = sm.misc[576 + sd * 384 + o];
      #pragma unroll
      for (int mi = 0; mi < 6; ++mi) {
        f32x4 acc = sd ? accQ1[mi] : accQ0[mi];
        #pragma unroll
        for (int j = 0; j < 4; ++j) {
          int x = mi * 16 + r4 + j;
          float mu = muA[x], rs = rsA[x];
          Qb[x * 200 + o] = (short)f2bf(rs * acc[j] - mu * rs * s1o + t1o);
        }
      }
    }
  }
  __syncthreads();

  // phase 5: att = Q_l * Q_r^T  (scaled), write XOR-swizzled fp32 over buf1
  {
    const int mi = wid >> 1;
    const int yb = (wid & 1) * 3;
    bhalf8 afa[6];
    #pragma unroll
    for (int k = 0; k < 6; ++k)
      afa[k] = *reinterpret_cast<const bhalf8*>(sm.buf1 + (mi * 16 + m16) * 200 + k * 32 + kc8);
    f32x4 accA[3];
    #pragma unroll
    for (int yt = 0; yt < 3; ++yt) {
      f32x4 acc = {0.f, 0.f, 0.f, 0.f};
      #pragma unroll
      for (int k = 0; k < 6; ++k) {
        bhalf8 bfy = *reinterpret_cast<const bhalf8*>(sm.buf2 + ((yb + yt) * 16 + m16) * 200 + k * 32 + kc8);
        acc = __builtin_amdgcn_mfma_f32_16x16x32_bf16(afa[k], bfy, acc, 0, 0, 0);
      }
      accA[yt] = acc;
    }
    __syncthreads();
    float* attf = reinterpret_cast<float*>(sm.buf1);
    const float scale = 0.07216878364870323f;   // 192^-0.5
    #pragma unroll
    for (int yt = 0; yt < 3; ++yt) {
      #pragma unroll
      for (int j = 0; j < 4; ++j) {
        int x = mi * 16 + r4 + j;
        int y = (yb + yt) * 16 + m16;
        attf[x * 96 + (y ^ (x & 31))] = accA[yt][j] * scale;
      }
    }
  }
  __syncthreads();

  // phase 6: dual softmax -> P_row (bf16 [x][y]) and P_colT (bf16 [y][x])
  {
    const float* attf = reinterpret_cast<const float*>(sm.buf1);
    short* Pr = sm.buf2;
    short* Pc = sm.buf2 + 9216;
    const int r = tid >> 3;     // 0..95
    const int p = tid & 7;
    {   // row softmax (over y), r = x
      float av[12];
      #pragma unroll
      for (int k = 0; k < 12; ++k)
        av[k] = attf[r * 96 + ((p * 12 + k) ^ (r & 31))];
      float mx = av[0];
      #pragma unroll
      for (int k = 1; k < 12; ++k) mx = fmaxf(mx, av[k]);
      mx = fmaxf(mx, __shfl_xor(mx, 1));
      mx = fmaxf(mx, __shfl_xor(mx, 2));
      mx = fmaxf(mx, __shfl_xor(mx, 4));
      float s = 0.f;
      #pragma unroll
      for (int k = 0; k < 12; ++k) { av[k] = __expf(av[k] - mx); s += av[k]; }
      s += __shfl_xor(s, 1); s += __shfl_xor(s, 2); s += __shfl_xor(s, 4);
      float inv = 1.f / s;
      #pragma unroll
      for (int k = 0; k < 12; k += 2) {
        unsigned u = (unsigned)f2bf(av[k] * inv) | ((unsigned)f2bf(av[k + 1] * inv) << 16);
        *reinterpret_cast<unsigned*>(Pr + r * 96 + p * 12 + k) = u;
      }
    }
    {   // column softmax (over x), r = y; write transposed
      float av[12];
      #pragma unroll
      for (int k = 0; k < 12; ++k) {
        int x = p * 12 + k;
        av[k] = attf[x * 96 + (r ^ (x & 31))];
      }
      float mx = av[0];
      #pragma unroll
      for (int k = 1; k < 12; ++k) mx = fmaxf(mx, av[k]);
      mx = fmaxf(mx, __shfl_xor(mx, 1));
      mx = fmaxf(mx, __shfl_xor(mx, 2));
      mx = fmaxf(mx, __shfl_xor(mx, 4));
      float s = 0.f;
      #pragma unroll
      for (int k = 0; k < 12; ++k) { av[k] = __expf(av[k] - mx); s += av[k]; }
      s += __shfl_xor(s, 1); s += __shfl_xor(s, 2); s += __shfl_xor(s, 4);
      float inv = 1.f / s;
      #pragma unroll
      for (int k = 0; k < 12; k += 2) {
        unsigned u = (unsigned)f2bf(av[k] * inv) | ((unsigned)f2bf(av[k + 1] * inv) << 16);
        *reinterpret_cast<unsigned*>(Pc + r * 96 + p * 12 + k) = u;
      }
    }
  }
  __syncthreads();

  // phase 7: F_r2l = P_row * V_r, F_l2r = P_colT * V_l   (D[m=x|y][n=c])
  f32x4 accF[6], accG[6];
  {
    const short* Pr = sm.buf2;
    const short* Pc = sm.buf2 + 9216;
    const int crow = wid * 16 + m16;
    bhalf8 vf[3], vg[3];
    #pragma unroll
    for (int k = 0; k < 3; ++k) {
      vf[k] = *reinterpret_cast<const bhalf8*>(sm.vtr + crow * 96 + k * 32 + kc8);
      vg[k] = *reinterpret_cast<const bhalf8*>(sm.vtl + crow * 96 + k * 32 + kc8);
    }
    #pragma unroll
    for (int xi = 0; xi < 6; ++xi) {
      f32x4 a1 = {0.f, 0.f, 0.f, 0.f}, a2 = {0.f, 0.f, 0.f, 0.f};
      #pragma unroll
      for (int k = 0; k < 3; ++k) {
        bhalf8 ap = *reinterpret_cast<const bhalf8*>(Pr + (xi * 16 + m16) * 96 + k * 32 + kc8);
        a1 = __builtin_amdgcn_mfma_f32_16x16x32_bf16(ap, vf[k], a1, 0, 0, 0);
        bhalf8 aq = *reinterpret_cast<const bhalf8*>(Pc + (xi * 16 + m16) * 96 + k * 32 + kc8);
        a2 = __builtin_amdgcn_mfma_f32_16x16x32_bf16(aq, vg[k], a2, 0, 0, 0);
      }
      accF[xi] = a1; accG[xi] = a2;
    }
  }
  __syncthreads();
  {
    const int cc2 = wid * 16 + m16;
    #pragma unroll
    for (int xi = 0; xi < 6; ++xi) {
      #pragma unroll
      for (int j = 0; j < 4; ++j) {
        int x = xi * 16 + r4 + j;
        sm.buf1[x * 200 + cc2] = (short)f2bf(accF[xi][j]);   // F_r2l [x][c]
        sm.buf2[x * 200 + cc2] = (short)f2bf(accG[xi][j]);   // F_l2r [y][c]
      }
    }
  }
  __syncthreads();

  // phase 8: epilogue  out = x + F*coef + temb   (x re-read from global, L2-hot)
  #pragma unroll
  for (int sd = 0; sd < 2; ++sd) {
    const float* xg = sd ? x_r : x_l;
    float* og = out + (sd ? HALF_OUT : 0);
    const short* Fb = sd ? sm.buf2 : sm.buf1;
    const float* coef = sm.misc + (sd ? 1920 : 1728);
    #pragma unroll
    for (int j = 0; j < 6; ++j) {
      int i4 = j * 768 + tid;
      int c  = i4 / 24;
      int w4 = i4 - c * 24;
      const float4 xv = *reinterpret_cast<const float4*>(xg + sliceBase + c * HWc + w4 * 4);
      float cf = coef[c];
      float tv = sm.misc[1536 + c];
      int fb = w4 * 4 * 200 + c;
      float4 ov;
      ov.x = xv.x + bf2f_s(Fb[fb      ]) * cf + tv;
      ov.y = xv.y + bf2f_s(Fb[fb + 200]) * cf + tv;
      ov.z = xv.z + bf2f_s(Fb[fb + 400]) * cf + tv;
      ov.w = xv.w + bf2f_s(Fb[fb + 600]) * cf + tv;
      *reinterpret_cast<float4*>(og + sliceBase + c * HWc + w4 * 4) = ov;
    }
  }
}

// -------------------------------------------------------------------- host ---
extern "C" void kernel_launch(void* const* d_in, const int* in_sizes, int n_in,
                              void* d_out, int out_size, void* d_ws, size_t ws_size,
                              hipStream_t stream)
{
  const float* t    = (const float*)d_in[0];
  const float* x_l  = (const float*)d_in[1];
  const float* x_r  = (const float*)d_in[2];
  const float* lnwl = (const float*)d_in[3];
  const float* lnbl = (const float*)d_in[4];
  const float* lnwr = (const float*)d_in[5];
  const float* lnbr = (const float*)d_in[6];
  const float* Wl1  = (const float*)d_in[7];
  const float* bl1  = (const float*)d_in[8];
  const float* Wr1  = (const float*)d_in[9];
  const float* br1  = (const float*)d_in[10];
  const float* Wl2  = (const float*)d_in[11];
  const float* bl2  = (const float*)d_in[12];
  const float* Wr2  = (const float*)d_in[13];
  const float* br2  = (const float*)d_in[14];
  const float* beta = (const float*)d_in[15];
  const float* gamma= (const float*)d_in[16];
  const float* Wt   = (const float*)d_in[17];
  const float* bt   = (const float*)d_in[18];
  float* out = (float*)d_out;

  char* ws = (char*)d_ws;
  short* W1l_b = (short*)ws;
  short* W1r_b = W1l_b + 36864;
  short* W2l_b = W1r_b + 36864;
  short* W2r_b = W2l_b + 36864;
  float* fws  = (float*)(ws + 4 * 73728);
  float* s1l  = fws;
  float* t1l  = fws + 192;
  float* s1r  = fws + 384;
  float* t1r  = fws + 576;
  float* temb = fws + 768;   // 3072 floats
  float* mt   = fws + 3840;  // 8192 floats

  setup1<<<610, 256, 0, stream>>>(t, lnwl, lnbl, lnwr, lnbr, Wl1, bl1, Wr1, br1,
                                  Wl2, Wr2, W1l_b, W1r_b, W2l_b, W2r_b,
                                  s1l, t1l, s1r, t1r, mt);
  setup2<<<12, 256, 0, stream>>>(mt, Wt, bt, temb);
  scam_main<<<1536, 768, 0, stream>>>(x_l, x_r, bl2, br2, beta, gamma,
                                      W1l_b, W1r_b, W2l_b, W2r_b,
                                      s1l, t1l, s1r, t1r, temb, out);
}